// Round 1
// baseline (1703.289 us; speedup 1.0000x reference)
//
#include <hip/hip_runtime.h>
#include <cmath>

#define BB 8
#define CC 256
#define CQ 64
#define NN 4096
constexpr float INV_N = 1.0f / 4096.0f;

// ---------------------------------------------------------------------------
// conv1x1 as GEMM: Y[b,o,n] = bias[o] + sum_c W[o,c] * X[b,c,n]
// grid: (N/64, Co/64, B), block 256. 64x64 tile, K-tile 64.
// ---------------------------------------------------------------------------
__global__ __launch_bounds__(256) void conv1x1_kernel(
    const float* __restrict__ X, const float* __restrict__ Wt,
    const float* __restrict__ bias, float* __restrict__ Y, int Co) {
  __shared__ float Ws[64][65];
  __shared__ float Xs[64][65];
  const int tid = threadIdx.x;
  const int n0 = blockIdx.x * 64;
  const int o0 = blockIdx.y * 64;
  const int b = blockIdx.z;
  const int tx = tid % 16, ty = tid / 16;
  float acc[4][4] = {};

  for (int c0 = 0; c0 < CC; c0 += 64) {
    // load 64x64 W tile (rows o, cols c)
    {
      const int r = tid / 16;
      const int cc = (tid % 16) * 4;
#pragma unroll
      for (int p = 0; p < 4; ++p) {
        const int row = r + p * 16;
        const float4 w4 = *reinterpret_cast<const float4*>(
            &Wt[(size_t)(o0 + row) * CC + c0 + cc]);
        Ws[row][cc + 0] = w4.x; Ws[row][cc + 1] = w4.y;
        Ws[row][cc + 2] = w4.z; Ws[row][cc + 3] = w4.w;
      }
    }
    // load 64x64 X tile (rows c, cols n)
    {
      const int r = tid / 16;
      const int nn = (tid % 16) * 4;
#pragma unroll
      for (int p = 0; p < 4; ++p) {
        const int row = r + p * 16;
        const float4 x4 = *reinterpret_cast<const float4*>(
            &X[((size_t)b * CC + c0 + row) * NN + n0 + nn]);
        Xs[row][nn + 0] = x4.x; Xs[row][nn + 1] = x4.y;
        Xs[row][nn + 2] = x4.z; Xs[row][nn + 3] = x4.w;
      }
    }
    __syncthreads();
#pragma unroll 16
    for (int kk = 0; kk < 64; ++kk) {
      float wv[4], xv[4];
#pragma unroll
      for (int i = 0; i < 4; ++i) wv[i] = Ws[ty * 4 + i][kk];
#pragma unroll
      for (int j = 0; j < 4; ++j) xv[j] = Xs[kk][tx * 4 + j];
#pragma unroll
      for (int i = 0; i < 4; ++i)
#pragma unroll
        for (int j = 0; j < 4; ++j) acc[i][j] += wv[i] * xv[j];
    }
    __syncthreads();
  }

#pragma unroll
  for (int i = 0; i < 4; ++i) {
    const int o = o0 + ty * 4 + i;
    const float bv = bias[o];
#pragma unroll
    for (int j = 0; j < 4; ++j) {
      Y[((size_t)b * Co + o) * NN + n0 + tx * 4 + j] = acc[i][j] + bv;
    }
  }
}

// ---------------------------------------------------------------------------
// Fused attention + gamma conv.
// S[n,m] = sum_c q[c,n]*k[c,m];  E = elu(S)/N;  out[c,m] = sum_n v[c,n]*E[n,m]
// final[o,m] = bg[o] + sum_c Wg[o,c]*out[c,m]
// grid: (N/32, B), block 256. Each block owns one 32-wide m slab, all 256 ch.
// ---------------------------------------------------------------------------
__global__ __launch_bounds__(256) void attn_kernel(
    const float* __restrict__ q, const float* __restrict__ k,
    const float* __restrict__ v, const float* __restrict__ Wg,
    const float* __restrict__ bg, float* __restrict__ out) {
  __shared__ float smem[8192];          // 32 KB, multi-purpose
  float* qs = smem;                     // [64 c][64 n]   (4096 floats)
  float* ks = smem + 4096;              // [64 c][32 m]   (2048 floats)
  float* Ss = smem + 6144;              // [64 n][32 m]   (2048 floats)

  const int tid = threadIdx.x;
  const int m0 = blockIdx.x * 32;
  const int b = blockIdx.y;

  // load k tile once: ks[c][m]
#pragma unroll
  for (int p = 0; p < 2; ++p) {
    const int idx = (p * 256 + tid) * 4;  // flat into [64][32]
    const int c = idx / 32, mm = idx % 32;
    const float4 kv = *reinterpret_cast<const float4*>(
        &k[((size_t)b * CQ + c) * NN + m0 + mm]);
    *reinterpret_cast<float4*>(&ks[idx]) = kv;
  }

  float acc[32];
#pragma unroll
  for (int j = 0; j < 32; ++j) acc[j] = 0.f;

  const int mj = tid % 32;
  const int ng = tid / 32;  // 0..7, owns n rows ng*8..ng*8+7 of S
  const float* vrow = &v[((size_t)b * CC + tid) * NN];

  for (int n0 = 0; n0 < NN; n0 += 64) {
    __syncthreads();  // prior iter's Ss reads done before rewrite
    // stage q tile: qs[c][n]
#pragma unroll
    for (int p = 0; p < 4; ++p) {
      const int idx = (p * 256 + tid) * 4;  // flat into [64][64]
      const int c = idx / 64, nn = idx % 64;
      const float4 qv = *reinterpret_cast<const float4*>(
          &q[((size_t)b * CQ + c) * NN + n0 + nn]);
      *reinterpret_cast<float4*>(&qs[idx]) = qv;
    }
    __syncthreads();

    // S compute: thread owns S[ng*8+e][mj], e=0..7
    float sacc[8];
#pragma unroll
    for (int e = 0; e < 8; ++e) sacc[e] = 0.f;
#pragma unroll 8
    for (int cc = 0; cc < 64; ++cc) {
      const float kval = ks[cc * 32 + mj];
      const float4 qa = *reinterpret_cast<const float4*>(&qs[cc * 64 + ng * 8]);
      const float4 qb = *reinterpret_cast<const float4*>(&qs[cc * 64 + ng * 8 + 4]);
      sacc[0] += qa.x * kval; sacc[1] += qa.y * kval;
      sacc[2] += qa.z * kval; sacc[3] += qa.w * kval;
      sacc[4] += qb.x * kval; sacc[5] += qb.y * kval;
      sacc[6] += qb.z * kval; sacc[7] += qb.w * kval;
    }
#pragma unroll
    for (int e = 0; e < 8; ++e) {
      float s = sacc[e];
      s = (s > 0.f) ? s : (__expf(s) - 1.f);  // elu
      Ss[(ng * 8 + e) * 32 + mj] = s * INV_N;
    }
    __syncthreads();

    // PV accumulate: thread owns channel c = tid
    const float* vp = vrow + n0;
#pragma unroll 4
    for (int nt4 = 0; nt4 < 64; nt4 += 4) {
      const float4 v4 = *reinterpret_cast<const float4*>(&vp[nt4]);
      const float vv[4] = {v4.x, v4.y, v4.z, v4.w};
#pragma unroll
      for (int u = 0; u < 4; ++u) {
        const float* srow = &Ss[(nt4 + u) * 32];
#pragma unroll
        for (int mm = 0; mm < 32; mm += 4) {
          const float4 s4 = *reinterpret_cast<const float4*>(&srow[mm]);
          acc[mm + 0] += vv[u] * s4.x;
          acc[mm + 1] += vv[u] * s4.y;
          acc[mm + 2] += vv[u] * s4.z;
          acc[mm + 3] += vv[u] * s4.w;
        }
      }
    }
  }

  // ---- epilogue: gamma conv on the block-local 256x32 out tile ----
  __syncthreads();
  float* Outs = smem;  // [256 c][32 m] = 8192 floats, reuses all of smem
#pragma unroll
  for (int mm = 0; mm < 32; mm += 4) {
    float4 a4 = make_float4(acc[mm], acc[mm + 1], acc[mm + 2], acc[mm + 3]);
    *reinterpret_cast<float4*>(&Outs[tid * 32 + mm]) = a4;
  }
  __syncthreads();

  float facc[32];
#pragma unroll
  for (int j = 0; j < 32; ++j) facc[j] = 0.f;
  const float* wrow = &Wg[(size_t)tid * CC];  // output channel o = tid
#pragma unroll 4
  for (int c0 = 0; c0 < CC; c0 += 4) {
    const float4 w4 = *reinterpret_cast<const float4*>(&wrow[c0]);
    const float wv[4] = {w4.x, w4.y, w4.z, w4.w};
#pragma unroll
    for (int u = 0; u < 4; ++u) {
      const float* orow = &Outs[(c0 + u) * 32];
#pragma unroll
      for (int mm = 0; mm < 32; mm += 4) {
        const float4 o4 = *reinterpret_cast<const float4*>(&orow[mm]);
        facc[mm + 0] += wv[u] * o4.x;
        facc[mm + 1] += wv[u] * o4.y;
        facc[mm + 2] += wv[u] * o4.z;
        facc[mm + 3] += wv[u] * o4.w;
      }
    }
  }
  const float bgv = bg[tid];
#pragma unroll
  for (int mm = 0; mm < 32; mm += 4) {
    float4 r4 = make_float4(facc[mm] + bgv, facc[mm + 1] + bgv,
                            facc[mm + 2] + bgv, facc[mm + 3] + bgv);
    *reinterpret_cast<float4*>(&out[((size_t)b * CC + tid) * NN + m0 + mm]) = r4;
  }
}

// ---------------------------------------------------------------------------
extern "C" void kernel_launch(void* const* d_in, const int* in_sizes, int n_in,
                              void* d_out, int out_size, void* d_ws,
                              size_t ws_size, hipStream_t stream) {
  const float* x  = (const float*)d_in[0];
  const float* wq = (const float*)d_in[1];
  const float* bq = (const float*)d_in[2];
  const float* wk = (const float*)d_in[3];
  const float* bk = (const float*)d_in[4];
  const float* wv = (const float*)d_in[5];
  const float* bv = (const float*)d_in[6];
  const float* wg = (const float*)d_in[7];
  const float* bg = (const float*)d_in[8];
  float* out = (float*)d_out;

  float* q = (float*)d_ws;                       //  8 MB
  float* k = q + (size_t)BB * CQ * NN;           //  8 MB
  float* v = k + (size_t)BB * CQ * NN;           // 32 MB

  conv1x1_kernel<<<dim3(NN / 64, CQ / 64, BB), 256, 0, stream>>>(x, wq, bq, q, CQ);
  conv1x1_kernel<<<dim3(NN / 64, CQ / 64, BB), 256, 0, stream>>>(x, wk, bk, k, CQ);
  conv1x1_kernel<<<dim3(NN / 64, CC / 64, BB), 256, 0, stream>>>(x, wv, bv, v, CC);
  attn_kernel<<<dim3(NN / 32, BB), 256, 0, stream>>>(q, k, v, wg, bg, out);
}

// Round 2
// 413.251 us; speedup vs baseline: 4.1217x; 4.1217x over previous
//
#include <hip/hip_runtime.h>
#include <cmath>

#define BB 8
#define CC 256
#define CQ 64
#define NN 4096
constexpr float INV_N = 1.0f / 4096.0f;

typedef __attribute__((ext_vector_type(8))) short short8;
typedef __attribute__((ext_vector_type(4))) short short4v;
typedef __attribute__((ext_vector_type(4))) float float4v;

__device__ __forceinline__ short f2bf(float f) {
  union { float f; unsigned u; } x; x.f = f;
  unsigned r = x.u + 0x7fffu + ((x.u >> 16) & 1u);
  return (short)(r >> 16);
}

// ---------------------------------------------------------------------------
// conv1x1 as fp32 GEMM (verified round 1), bf16 output.
// MODE 0: write transposed  Yt[b][n][Co]  (Co==64, for q/k)
// MODE 1: write natural     Yn[b][o][n]   (for v)
// ---------------------------------------------------------------------------
__global__ __launch_bounds__(256) void conv1x1_kernel(
    const float* __restrict__ X, const float* __restrict__ Wt,
    const float* __restrict__ bias, short* __restrict__ Y, int Co, int MODE) {
  __shared__ float Ws[64][65];
  __shared__ float Xs[64][65];
  const int tid = threadIdx.x;
  const int n0 = blockIdx.x * 64;
  const int o0 = blockIdx.y * 64;
  const int b = blockIdx.z;
  const int tx = tid % 16, ty = tid / 16;
  float acc[4][4] = {};

  for (int c0 = 0; c0 < CC; c0 += 64) {
    {
      const int r = tid / 16;
      const int cc = (tid % 16) * 4;
#pragma unroll
      for (int p = 0; p < 4; ++p) {
        const int row = r + p * 16;
        const float4 w4 = *reinterpret_cast<const float4*>(
            &Wt[(size_t)(o0 + row) * CC + c0 + cc]);
        Ws[row][cc + 0] = w4.x; Ws[row][cc + 1] = w4.y;
        Ws[row][cc + 2] = w4.z; Ws[row][cc + 3] = w4.w;
      }
    }
    {
      const int r = tid / 16;
      const int nn = (tid % 16) * 4;
#pragma unroll
      for (int p = 0; p < 4; ++p) {
        const int row = r + p * 16;
        const float4 x4 = *reinterpret_cast<const float4*>(
            &X[((size_t)b * CC + c0 + row) * NN + n0 + nn]);
        Xs[row][nn + 0] = x4.x; Xs[row][nn + 1] = x4.y;
        Xs[row][nn + 2] = x4.z; Xs[row][nn + 3] = x4.w;
      }
    }
    __syncthreads();
#pragma unroll 16
    for (int kk = 0; kk < 64; ++kk) {
      float wv[4], xv[4];
#pragma unroll
      for (int i = 0; i < 4; ++i) wv[i] = Ws[ty * 4 + i][kk];
#pragma unroll
      for (int j = 0; j < 4; ++j) xv[j] = Xs[kk][tx * 4 + j];
#pragma unroll
      for (int i = 0; i < 4; ++i)
#pragma unroll
        for (int j = 0; j < 4; ++j) acc[i][j] += wv[i] * xv[j];
    }
    __syncthreads();
  }

  if (MODE == 0) {
    // transposed bf16: Yt[(b*NN + n)*64 + o]
#pragma unroll
    for (int i = 0; i < 4; ++i) {
      const int o = o0 + ty * 4 + i;
      const float bv = bias[o];
#pragma unroll
      for (int j = 0; j < 4; ++j) {
        const int n = n0 + tx * 4 + j;
        Y[((size_t)b * NN + n) * 64 + o] = f2bf(acc[i][j] + bv);
      }
    }
  } else {
    // natural bf16: Yn[(b*Co + o)*NN + n], 4 packed per store
#pragma unroll
    for (int i = 0; i < 4; ++i) {
      const int o = o0 + ty * 4 + i;
      const float bv = bias[o];
      short4v pk;
      pk.x = f2bf(acc[i][0] + bv); pk.y = f2bf(acc[i][1] + bv);
      pk.z = f2bf(acc[i][2] + bv); pk.w = f2bf(acc[i][3] + bv);
      *reinterpret_cast<short4v*>(
          &Y[((size_t)b * Co + o) * NN + n0 + tx * 4]) = pk;
    }
  }
}

// ---------------------------------------------------------------------------
// Fused MFMA attention + gamma conv.
// Block: 256 threads (4 waves), owns m-tile of 64 cols, all 256 channels.
// S[64n x 64m] per iter via mfma16x16x32 (A=q^T from qs[n][c], B=k from ks[m][c])
// E=elu(S)/N -> Es[m][n] bf16 (B-operand layout for PV)
// PV: acc[256c x 64m] += V[c][n] @ E  (A-frags direct from global v_bf16)
// Epilogue: Outs[m][c] bf16 -> gamma MFMA with Wg, + bias -> out fp32.
// ---------------------------------------------------------------------------
__global__ __launch_bounds__(256) void attn_kernel(
    const short* __restrict__ qt, const short* __restrict__ kt,
    const short* __restrict__ vbf, const float* __restrict__ Wg,
    const float* __restrict__ bg, float* __restrict__ out) {
  __shared__ short smem[17024];          // 34048 B
  short* qs = smem;                      // [64][72]
  short* ks = smem + 4608;               // [64][72]
  short* Es = smem + 9216;               // [64 m][72 n]
  short* Outs = smem;                    // [64 m][264 c]  (epilogue alias)

  const int tid = threadIdx.x;
  const int wv = tid >> 6;
  const int lane = tid & 63;
  const int quad = lane >> 4;
  const int l16 = lane & 15;
  const int m0 = blockIdx.x * 64;
  const int b = blockIdx.y;

  // stage ks once: rows m (block-local), 64 c contiguous
  {
    const short* ksrc = kt + ((size_t)b * NN + m0) * 64;
#pragma unroll
    for (int p = 0; p < 2; ++p) {
      const int t = p * 256 + tid;
      const int row = t >> 3, coff = (t & 7) * 8;
      *reinterpret_cast<short8*>(&ks[row * 72 + coff]) =
          *reinterpret_cast<const short8*>(&ksrc[row * 64 + coff]);
    }
  }

  float4v acc[4][4];
#pragma unroll
  for (int i = 0; i < 4; ++i)
#pragma unroll
    for (int j = 0; j < 4; ++j) acc[i][j] = float4v{0.f, 0.f, 0.f, 0.f};

  for (int it = 0; it < 64; ++it) {
    const int n0 = it * 64;
    // stage qs: rows n (tile-local), 64 c contiguous
    {
      const short* qsrc = qt + ((size_t)b * NN + n0) * 64;
#pragma unroll
      for (int p = 0; p < 2; ++p) {
        const int t = p * 256 + tid;
        const int row = t >> 3, coff = (t & 7) * 8;
        *reinterpret_cast<short8*>(&qs[row * 72 + coff]) =
            *reinterpret_cast<const short8*>(&qsrc[row * 64 + coff]);
      }
    }
    __syncthreads();

    // ---- S = q^T k ; wave owns S rows n in [wv*16, wv*16+16), all 64 m ----
    const short8 aq0 = *reinterpret_cast<const short8*>(
        &qs[(wv * 16 + l16) * 72 + quad * 8]);
    const short8 aq1 = *reinterpret_cast<const short8*>(
        &qs[(wv * 16 + l16) * 72 + 32 + quad * 8]);
    float4v sacc[4];
#pragma unroll
    for (int tm = 0; tm < 4; ++tm) {
      const short8 bk0 = *reinterpret_cast<const short8*>(
          &ks[(tm * 16 + l16) * 72 + quad * 8]);
      const short8 bk1 = *reinterpret_cast<const short8*>(
          &ks[(tm * 16 + l16) * 72 + 32 + quad * 8]);
      float4v s = {0.f, 0.f, 0.f, 0.f};
      s = __builtin_amdgcn_mfma_f32_16x16x32_bf16(aq0, bk0, s, 0, 0, 0);
      s = __builtin_amdgcn_mfma_f32_16x16x32_bf16(aq1, bk1, s, 0, 0, 0);
      sacc[tm] = s;
    }
    // elu/N -> Es[m][n] (4 consecutive n per lane-reg-group)
#pragma unroll
    for (int tm = 0; tm < 4; ++tm) {
      short4v pk;
#pragma unroll
      for (int r = 0; r < 4; ++r) {
        float sv = sacc[tm][r];
        sv = (sv > 0.f) ? sv : (__expf(sv) - 1.f);
        pk[r] = f2bf(sv * INV_N);
      }
      *reinterpret_cast<short4v*>(
          &Es[(tm * 16 + l16) * 72 + wv * 16 + quad * 4]) = pk;
    }
    __syncthreads();

    // ---- PV: wave owns channels [wv*64, wv*64+64) x all 64 m ----
    short8 be[4][2];
#pragma unroll
    for (int tm = 0; tm < 4; ++tm) {
      be[tm][0] = *reinterpret_cast<const short8*>(
          &Es[(tm * 16 + l16) * 72 + quad * 8]);
      be[tm][1] = *reinterpret_cast<const short8*>(
          &Es[(tm * 16 + l16) * 72 + 32 + quad * 8]);
    }
#pragma unroll
    for (int tc = 0; tc < 4; ++tc) {
      const int c = wv * 64 + tc * 16 + l16;
      const short* vp = &vbf[((size_t)b * CC + c) * NN + n0 + quad * 8];
      const short8 av0 = *reinterpret_cast<const short8*>(vp);
      const short8 av1 = *reinterpret_cast<const short8*>(vp + 32);
#pragma unroll
      for (int tm = 0; tm < 4; ++tm) {
        acc[tc][tm] =
            __builtin_amdgcn_mfma_f32_16x16x32_bf16(av0, be[tm][0], acc[tc][tm], 0, 0, 0);
        acc[tc][tm] =
            __builtin_amdgcn_mfma_f32_16x16x32_bf16(av1, be[tm][1], acc[tc][tm], 0, 0, 0);
      }
    }
  }

  // ---- epilogue: gamma conv via MFMA ----
  __syncthreads();
  // acc[tc][tm] C-layout: c = wv*64 + tc*16 + quad*4 + r, m = tm*16 + l16
#pragma unroll
  for (int tc = 0; tc < 4; ++tc)
#pragma unroll
    for (int tm = 0; tm < 4; ++tm) {
      short4v pk;
#pragma unroll
      for (int r = 0; r < 4; ++r) pk[r] = f2bf(acc[tc][tm][r]);
      *reinterpret_cast<short4v*>(
          &Outs[(tm * 16 + l16) * 264 + wv * 64 + tc * 16 + quad * 4]) = pk;
    }
  __syncthreads();

  // final[o][m] = Wg[o][:] @ Outs[:][m]; wave owns o in [wv*64, wv*64+64)
#pragma unroll
  for (int i = 0; i < 4; ++i)
#pragma unroll
    for (int j = 0; j < 4; ++j) acc[i][j] = float4v{0.f, 0.f, 0.f, 0.f};

  for (int ks8 = 0; ks8 < 8; ++ks8) {
    short8 ag[4];
#pragma unroll
    for (int to = 0; to < 4; ++to) {
      const float* wp =
          &Wg[(size_t)(wv * 64 + to * 16 + l16) * CC + ks8 * 32 + quad * 8];
      const float4v w0 = *reinterpret_cast<const float4v*>(wp);
      const float4v w1 = *reinterpret_cast<const float4v*>(wp + 4);
      short8 a;
      a[0] = f2bf(w0[0]); a[1] = f2bf(w0[1]); a[2] = f2bf(w0[2]); a[3] = f2bf(w0[3]);
      a[4] = f2bf(w1[0]); a[5] = f2bf(w1[1]); a[6] = f2bf(w1[2]); a[7] = f2bf(w1[3]);
      ag[to] = a;
    }
    short8 bo[4];
#pragma unroll
    for (int tm = 0; tm < 4; ++tm)
      bo[tm] = *reinterpret_cast<const short8*>(
          &Outs[(tm * 16 + l16) * 264 + ks8 * 32 + quad * 8]);
#pragma unroll
    for (int to = 0; to < 4; ++to)
#pragma unroll
      for (int tm = 0; tm < 4; ++tm)
        acc[to][tm] =
            __builtin_amdgcn_mfma_f32_16x16x32_bf16(ag[to], bo[tm], acc[to][tm], 0, 0, 0);
  }

#pragma unroll
  for (int to = 0; to < 4; ++to) {
#pragma unroll
    for (int r = 0; r < 4; ++r) {
      const int o = wv * 64 + to * 16 + quad * 4 + r;
      const float bgv = bg[o];
#pragma unroll
      for (int tm = 0; tm < 4; ++tm) {
        out[((size_t)b * CC + o) * NN + m0 + tm * 16 + l16] =
            acc[to][tm][r] + bgv;
      }
    }
  }
}

// ---------------------------------------------------------------------------
extern "C" void kernel_launch(void* const* d_in, const int* in_sizes, int n_in,
                              void* d_out, int out_size, void* d_ws,
                              size_t ws_size, hipStream_t stream) {
  const float* x  = (const float*)d_in[0];
  const float* wq = (const float*)d_in[1];
  const float* bq = (const float*)d_in[2];
  const float* wk = (const float*)d_in[3];
  const float* bk = (const float*)d_in[4];
  const float* wv = (const float*)d_in[5];
  const float* bv = (const float*)d_in[6];
  const float* wg = (const float*)d_in[7];
  const float* bg = (const float*)d_in[8];
  float* out = (float*)d_out;

  short* qt  = (short*)d_ws;                     // [B][N][64] bf16, 4 MB
  short* kt  = qt + (size_t)BB * NN * CQ;        // 4 MB
  short* vbf = kt + (size_t)BB * NN * CQ;        // [B][C][N] bf16, 16 MB

  conv1x1_kernel<<<dim3(NN / 64, 1, BB), 256, 0, stream>>>(x, wq, bq, qt, CQ, 0);
  conv1x1_kernel<<<dim3(NN / 64, 1, BB), 256, 0, stream>>>(x, wk, bk, kt, CQ, 0);
  conv1x1_kernel<<<dim3(NN / 64, CC / 64, BB), 256, 0, stream>>>(x, wv, bv, vbf, CC, 1);
  attn_kernel<<<dim3(NN / 64, BB), 256, 0, stream>>>(qt, kt, vbf, wg, bg, out);
}

// Round 3
// 283.733 us; speedup vs baseline: 6.0031x; 1.4565x over previous
//
#include <hip/hip_runtime.h>
#include <cmath>

#define BB 8
#define CC 256
#define CQ 64
#define NN 4096
constexpr float INV_N = 1.0f / 4096.0f;

typedef __attribute__((ext_vector_type(8))) short short8;
typedef __attribute__((ext_vector_type(4))) short short4v;
typedef __attribute__((ext_vector_type(4))) float float4v;

__device__ __forceinline__ short f2bf(float f) {
  union { float f; unsigned u; } x; x.f = f;
  unsigned r = x.u + 0x7fffu + ((x.u >> 16) & 1u);
  return (short)(r >> 16);
}

// ---------------------------------------------------------------------------
// Fused q/k/v conv1x1 via bf16 MFMA. Reads x once, stages xt[n][c] bf16 in
// LDS, loops 6 chunks of 64 output channels (q | k | v0..v3).
// Outputs: qt/kt transposed [b][n][64]; vbf natural [b][c][n].
// grid (NN/64, B), 256 threads.
// ---------------------------------------------------------------------------
__global__ __launch_bounds__(256, 2) void qkv_kernel(
    const float* __restrict__ X,
    const float* __restrict__ wq, const float* __restrict__ bq,
    const float* __restrict__ wk, const float* __restrict__ bk,
    const float* __restrict__ wv, const float* __restrict__ bv,
    short* __restrict__ qt, short* __restrict__ kt, short* __restrict__ vbf) {
  __shared__ short xt[64 * 272];   // [n][c] bf16, stride 272 (16B-aligned rows)
  __shared__ short Os[64 * 72];    // v-output staging [o][n]
  const int tid = threadIdx.x;
  const int wid = tid >> 6;
  const int lane = tid & 63, quad = lane >> 4, l16 = lane & 15;
  const int n0 = blockIdx.x * 64, b = blockIdx.y;

  // stage x tile -> xt[n][c] bf16 (transpose, fp32->bf16)
#pragma unroll 4
  for (int p = 0; p < 16; ++p) {
    const int idx = p * 256 + tid;
    const int c = idx >> 4;
    const int n4 = (idx & 15) * 4;
    const float4 x4 = *reinterpret_cast<const float4*>(
        &X[((size_t)b * CC + c) * NN + n0 + n4]);
    xt[(n4 + 0) * 272 + c] = f2bf(x4.x);
    xt[(n4 + 1) * 272 + c] = f2bf(x4.y);
    xt[(n4 + 2) * 272 + c] = f2bf(x4.z);
    xt[(n4 + 3) * 272 + c] = f2bf(x4.w);
  }
  __syncthreads();

  for (int ch = 0; ch < 6; ++ch) {
    const float* W; const float* bias; int obase;
    if (ch == 0)      { W = wq; bias = bq; obase = 0; }
    else if (ch == 1) { W = wk; bias = bk; obase = 0; }
    else { W = wv + (size_t)(ch - 2) * 64 * CC; bias = bv + (ch - 2) * 64; obase = (ch - 2) * 64; }

    float4v acc[4];
#pragma unroll
    for (int tm = 0; tm < 4; ++tm) acc[tm] = float4v{0.f, 0.f, 0.f, 0.f};

#pragma unroll
    for (int kk = 0; kk < 8; ++kk) {
      const float* wp = &W[(size_t)(wid * 16 + l16) * CC + kk * 32 + quad * 8];
      const float4v w0 = *reinterpret_cast<const float4v*>(wp);
      const float4v w1 = *reinterpret_cast<const float4v*>(wp + 4);
      short8 a;
      a[0] = f2bf(w0[0]); a[1] = f2bf(w0[1]); a[2] = f2bf(w0[2]); a[3] = f2bf(w0[3]);
      a[4] = f2bf(w1[0]); a[5] = f2bf(w1[1]); a[6] = f2bf(w1[2]); a[7] = f2bf(w1[3]);
#pragma unroll
      for (int tm = 0; tm < 4; ++tm) {
        const short8 bfrag = *reinterpret_cast<const short8*>(
            &xt[(tm * 16 + l16) * 272 + kk * 32 + quad * 8]);
        acc[tm] = __builtin_amdgcn_mfma_f32_16x16x32_bf16(a, bfrag, acc[tm], 0, 0, 0);
      }
    }

    // C layout: row o_local = wid*16 + quad*4 + r, col n_local = tm*16 + l16
    if (ch < 2) {
      short* dst = (ch == 0) ? qt : kt;
#pragma unroll
      for (int tm = 0; tm < 4; ++tm) {
        short4v pk;
#pragma unroll
        for (int r = 0; r < 4; ++r)
          pk[r] = f2bf(acc[tm][r] + bias[wid * 16 + quad * 4 + r]);
        *reinterpret_cast<short4v*>(
            &dst[((size_t)b * NN + n0 + tm * 16 + l16) * 64 + wid * 16 + quad * 4]) = pk;
      }
    } else {
      __syncthreads();  // previous chunk's Os reads complete
#pragma unroll
      for (int tm = 0; tm < 4; ++tm)
#pragma unroll
        for (int r = 0; r < 4; ++r)
          Os[(wid * 16 + quad * 4 + r) * 72 + tm * 16 + l16] =
              f2bf(acc[tm][r] + bias[wid * 16 + quad * 4 + r]);
      __syncthreads();
      const int o = tid >> 2, ng = (tid & 3) * 16;
      const short8 s0 = *reinterpret_cast<const short8*>(&Os[o * 72 + ng]);
      const short8 s1 = *reinterpret_cast<const short8*>(&Os[o * 72 + ng + 8]);
      short* vp = &vbf[((size_t)b * CC + obase + o) * NN + n0 + ng];
      *reinterpret_cast<short8*>(vp) = s0;
      *reinterpret_cast<short8*>(vp + 8) = s1;
    }
  }
}

// ---------------------------------------------------------------------------
// Fused MFMA attention + gamma conv, v2:
//  - k B-frags in registers (no ks LDS)
//  - q A-frags direct from global qt, prefetched 1 iter ahead
//  - v A-frags issued at iter top, consumed after the barrier
//  - Es double-buffered -> ONE barrier per iteration
// grid (NN/64, B), 256 threads (4 waves).
// ---------------------------------------------------------------------------
__global__ __launch_bounds__(256, 2) void attn_kernel(
    const short* __restrict__ qt, const short* __restrict__ kt,
    const short* __restrict__ vbf, const float* __restrict__ Wg,
    const float* __restrict__ bg, float* __restrict__ out) {
  __shared__ short smem[16896];   // 33792 B
  short* Es0 = smem;              // [64 m][72 n]
  short* Es1 = smem + 4608;
  short* Outs = smem;             // [64 m][264 c] epilogue alias

  const int tid = threadIdx.x;
  const int wid = tid >> 6;
  const int lane = tid & 63, quad = lane >> 4, l16 = lane & 15;
  const int m0 = blockIdx.x * 64, b = blockIdx.y;

  // k fragments: resident in registers for the whole kernel
  short8 bkf[4][2];
#pragma unroll
  for (int tm = 0; tm < 4; ++tm)
#pragma unroll
    for (int kk = 0; kk < 2; ++kk)
      bkf[tm][kk] = *reinterpret_cast<const short8*>(
          &kt[((size_t)b * NN + m0 + tm * 16 + l16) * 64 + kk * 32 + quad * 8]);

  const short* qrow = &qt[((size_t)b * NN + wid * 16 + l16) * 64 + quad * 8];
  const short* vrow[4];
#pragma unroll
  for (int tc = 0; tc < 4; ++tc)
    vrow[tc] = &vbf[((size_t)b * CC + wid * 64 + tc * 16 + l16) * NN + quad * 8];

  float4v acc[4][4];
#pragma unroll
  for (int i = 0; i < 4; ++i)
#pragma unroll
    for (int j = 0; j < 4; ++j) acc[i][j] = float4v{0.f, 0.f, 0.f, 0.f};

  // prefetch iter-0 q fragments
  short8 aq0 = *reinterpret_cast<const short8*>(qrow);
  short8 aq1 = *reinterpret_cast<const short8*>(qrow + 32);

  for (int it = 0; it < 64; ++it) {
    const int nb = it * 64;
    short* Esw = (it & 1) ? Es1 : Es0;

    // v fragments for THIS iter — issued early, used after the barrier
    short8 av[4][2];
#pragma unroll
    for (int tc = 0; tc < 4; ++tc) {
      av[tc][0] = *reinterpret_cast<const short8*>(vrow[tc] + nb);
      av[tc][1] = *reinterpret_cast<const short8*>(vrow[tc] + nb + 32);
    }

    // S = q^T k (K=64 via two MFMAs per m-tile)
    float4v s[4];
#pragma unroll
    for (int tm = 0; tm < 4; ++tm) {
      float4v t = {0.f, 0.f, 0.f, 0.f};
      t = __builtin_amdgcn_mfma_f32_16x16x32_bf16(aq0, bkf[tm][0], t, 0, 0, 0);
      t = __builtin_amdgcn_mfma_f32_16x16x32_bf16(aq1, bkf[tm][1], t, 0, 0, 0);
      s[tm] = t;
    }

    // prefetch next iter's q fragments (reads spill into kt region at the
    // very end — allocated workspace, values unused)
    const short8 aq0n = *reinterpret_cast<const short8*>(qrow + (size_t)(it + 1) * 64 * 64);
    const short8 aq1n = *reinterpret_cast<const short8*>(qrow + (size_t)(it + 1) * 64 * 64 + 32);

    // elu/N -> Es (C layout: m = tm*16+l16, n = wid*16+quad*4+r)
#pragma unroll
    for (int tm = 0; tm < 4; ++tm) {
      short4v pk;
#pragma unroll
      for (int r = 0; r < 4; ++r) {
        float sv = s[tm][r];
        sv = (sv > 0.f) ? sv : (__expf(sv) - 1.f);
        pk[r] = f2bf(sv * INV_N);
      }
      *reinterpret_cast<short4v*>(
          &Esw[(tm * 16 + l16) * 72 + wid * 16 + quad * 4]) = pk;
    }
    __syncthreads();

    // PV: acc[c-tile][m-tile] += V E
#pragma unroll
    for (int tm = 0; tm < 4; ++tm) {
      const short8 be0 = *reinterpret_cast<const short8*>(
          &Esw[(tm * 16 + l16) * 72 + quad * 8]);
      const short8 be1 = *reinterpret_cast<const short8*>(
          &Esw[(tm * 16 + l16) * 72 + 32 + quad * 8]);
#pragma unroll
      for (int tc = 0; tc < 4; ++tc) {
        acc[tc][tm] = __builtin_amdgcn_mfma_f32_16x16x32_bf16(av[tc][0], be0, acc[tc][tm], 0, 0, 0);
        acc[tc][tm] = __builtin_amdgcn_mfma_f32_16x16x32_bf16(av[tc][1], be1, acc[tc][tm], 0, 0, 0);
      }
    }
    aq0 = aq0n; aq1 = aq1n;
  }

  // ---- epilogue: gamma conv via MFMA ----
  __syncthreads();
#pragma unroll
  for (int tc = 0; tc < 4; ++tc)
#pragma unroll
    for (int tm = 0; tm < 4; ++tm) {
      short4v pk;
#pragma unroll
      for (int r = 0; r < 4; ++r) pk[r] = f2bf(acc[tc][tm][r]);
      *reinterpret_cast<short4v*>(
          &Outs[(tm * 16 + l16) * 264 + wid * 64 + tc * 16 + quad * 4]) = pk;
    }
  __syncthreads();

#pragma unroll
  for (int i = 0; i < 4; ++i)
#pragma unroll
    for (int j = 0; j < 4; ++j) acc[i][j] = float4v{0.f, 0.f, 0.f, 0.f};

  for (int ks8 = 0; ks8 < 8; ++ks8) {
    short8 ag[4];
#pragma unroll
    for (int to = 0; to < 4; ++to) {
      const float* wp =
          &Wg[(size_t)(wid * 64 + to * 16 + l16) * CC + ks8 * 32 + quad * 8];
      const float4v w0 = *reinterpret_cast<const float4v*>(wp);
      const float4v w1 = *reinterpret_cast<const float4v*>(wp + 4);
      short8 a;
      a[0] = f2bf(w0[0]); a[1] = f2bf(w0[1]); a[2] = f2bf(w0[2]); a[3] = f2bf(w0[3]);
      a[4] = f2bf(w1[0]); a[5] = f2bf(w1[1]); a[6] = f2bf(w1[2]); a[7] = f2bf(w1[3]);
      ag[to] = a;
    }
    short8 bo[4];
#pragma unroll
    for (int tm = 0; tm < 4; ++tm)
      bo[tm] = *reinterpret_cast<const short8*>(
          &Outs[(tm * 16 + l16) * 264 + ks8 * 32 + quad * 8]);
#pragma unroll
    for (int to = 0; to < 4; ++to)
#pragma unroll
      for (int tm = 0; tm < 4; ++tm)
        acc[to][tm] =
            __builtin_amdgcn_mfma_f32_16x16x32_bf16(ag[to], bo[tm], acc[to][tm], 0, 0, 0);
  }

#pragma unroll
  for (int to = 0; to < 4; ++to) {
#pragma unroll
    for (int r = 0; r < 4; ++r) {
      const int o = wid * 64 + to * 16 + quad * 4 + r;
      const float bgv = bg[o];
#pragma unroll
      for (int tm = 0; tm < 4; ++tm) {
        out[((size_t)b * CC + o) * NN + m0 + tm * 16 + l16] =
            acc[to][tm][r] + bgv;
      }
    }
  }
}

// ---------------------------------------------------------------------------
extern "C" void kernel_launch(void* const* d_in, const int* in_sizes, int n_in,
                              void* d_out, int out_size, void* d_ws,
                              size_t ws_size, hipStream_t stream) {
  const float* x  = (const float*)d_in[0];
  const float* wq = (const float*)d_in[1];
  const float* bq = (const float*)d_in[2];
  const float* wk = (const float*)d_in[3];
  const float* bk = (const float*)d_in[4];
  const float* wv = (const float*)d_in[5];
  const float* bv = (const float*)d_in[6];
  const float* wg = (const float*)d_in[7];
  const float* bg = (const float*)d_in[8];
  float* out = (float*)d_out;

  short* qt  = (short*)d_ws;                     // [B][N][64] bf16, 4 MB
  short* kt  = qt + (size_t)BB * NN * CQ;        // 4 MB
  short* vbf = kt + (size_t)BB * NN * CQ;        // [B][C][N] bf16, 16 MB

  qkv_kernel<<<dim3(NN / 64, BB), 256, 0, stream>>>(x, wq, bq, wk, bk, wv, bv,
                                                    qt, kt, vbf);
  attn_kernel<<<dim3(NN / 64, BB), 256, 0, stream>>>(qt, kt, vbf, wg, bg, out);
}